// Round 2
// baseline (933.679 us; speedup 1.0000x reference)
//
#include <hip/hip_runtime.h>
#include <hip/hip_bf16.h>

#define VN 50000
#define EN 800000
#define BN 4
#define CINN 64
#define COUTN 128
#define KN 4
#define FN 256  // BN * CINN

typedef __attribute__((ext_vector_type(8))) short short8;
typedef __attribute__((ext_vector_type(8))) unsigned short ushort8;
typedef __attribute__((ext_vector_type(4))) float floatx4;

__device__ __forceinline__ float bf2f(unsigned short u) {
    union { unsigned int i; float f; } c;
    c.i = ((unsigned int)u) << 16;
    return c.f;
}
__device__ __forceinline__ unsigned short f2bf(float f) {
    __hip_bfloat16 h = __float2bfloat16(f);
    return *reinterpret_cast<unsigned short*>(&h);
}

#define RP_BLOCKS 196    // (VN+1+255)/256
#define WT_BLOCKS 128    // 128*256/256
#define EP_BLOCKS 3125   // EN/256
#define TP_BX 782        // (VN+63)/64
#define TP_BLOCKS (TP_BX * 4)
#define SPMM_GRID 2048   // persistent-ish; queues drained via atomics

// ---------------------------------------------------------------------------
// Fused setup: [0,RP) row_ptr lower_bound (+ queue-counter zeroing);
// [RP,RP+WT) wT transpose+bf16; [.., +EP) packed (col,val) edge data;
// rest: 64x64 x-transpose fp32->bf16 into SLICED layout x0[plane][v][32],
// plane = f>>5 (8 planes of 3.2MB each).
// ---------------------------------------------------------------------------
__global__ __launch_bounds__(256) void setup_fused(const int* __restrict__ rows,
                                                   int* __restrict__ row_ptr,
                                                   const float* __restrict__ w,
                                                   ushort* __restrict__ wT,
                                                   const float* __restrict__ x,
                                                   ushort* __restrict__ x0,
                                                   const int* __restrict__ cols,
                                                   const float* __restrict__ vals,
                                                   unsigned long long* __restrict__ epack,
                                                   int* __restrict__ qctr) {
    __shared__ float tile[64][65];
    int blk = blockIdx.x;
    int tid = threadIdx.x;
    if (blk < RP_BLOCKS) {
        if (blk == 0 && tid < 24) qctr[tid] = 0;  // 3 passes x 8 slice queues
        int v = blk * 256 + tid;
        if (v > VN) return;
        int lo = 0, hi = EN;
        while (lo < hi) {
            int mid = (lo + hi) >> 1;
            if (rows[mid] < v) lo = mid + 1; else hi = mid;
        }
        row_ptr[v] = lo;
        return;
    }
    if (blk < RP_BLOCKS + WT_BLOCKS) {
        int idx = (blk - RP_BLOCKS) * 256 + tid;  // 32768 total
        int o = idx >> 8;
        int kk = idx & 255;
        wT[idx] = f2bf(w[(size_t)kk * COUTN + o]);
        return;
    }
    if (blk < RP_BLOCKS + WT_BLOCKS + EP_BLOCKS) {
        int idx = (blk - RP_BLOCKS - WT_BLOCKS) * 256 + tid;  // 800000 total
        unsigned int c = (unsigned int)cols[idx];
        unsigned int wv = __float_as_uint(vals[idx]);
        epack[idx] = ((unsigned long long)wv << 32) | (unsigned long long)c;
        return;
    }
    int t = blk - RP_BLOCKS - WT_BLOCKS - EP_BLOCKS;
    int v0 = (t % TP_BX) * 64;
    int f0 = (t / TP_BX) * 64;
    int tx = tid & 63;
    int ty = tid >> 6;
#pragma unroll
    for (int r = 0; r < 16; ++r) {
        int f = f0 + ty + r * 4;
        int v = v0 + tx;
        if (v < VN) tile[ty + r * 4][tx] = x[(size_t)f * VN + v];
    }
    __syncthreads();
#pragma unroll
    for (int r = 0; r < 16; ++r) {
        int v = v0 + ty + r * 4;
        int f = f0 + tx;
        if (v < VN)
            x0[((size_t)(f >> 5) * VN + v) * 32 + (f & 31)] = f2bf(tile[tx][ty + r * 4]);
    }
}

// ---------------------------------------------------------------------------
// XCD-pinned sliced SpMM. Each workgroup reads its physical XCC id
// (s_getreg HW_REG_XCC_ID, id=20 width=4 — HW-verified on MI355X) and pops
// 64-row blocks from the per-slice atomic queue matching its XCD. Slice s
// gathers ONLY from plane s (3.2MB, fits the XCD's 4MB L2), so after first
// touch gathers are L2 hits by construction. Work-stealing from other
// queues after own queue drains guarantees completion even if XCC_ID
// misbehaves (degrades to L3-bound, not wrong/hung).
// Wave = 16 groups x 4 lanes; group owns a row; lane owns 8 features
// (16B gather; group gathers one 64B line per edge). 4-deep edge pipeline,
// two accumulators. All loads/stores NORMAL (round-1's nt hints caused the
// 135MB/pass HBM fetch regression).
// ---------------------------------------------------------------------------
__global__ __launch_bounds__(256) void spmm_sliced(ushort* __restrict__ out,
                                                   const ushort* __restrict__ z,
                                                   const ushort* __restrict__ prev,
                                                   const int* __restrict__ row_ptr,
                                                   const unsigned long long* __restrict__ epack,
                                                   int* __restrict__ qctr,
                                                   float alpha, float beta) {
    __shared__ int sIdx;
    int tid = threadIdx.x;
    int lane = tid & 63;
    int g = lane >> 2;          // group 0..15 within wave
    int l = lane & 3;           // lane in group: features l*8 .. l*8+7 of slice
    int rbase = (tid >> 6) * 16 + g;
    // HW_REG_XCC_ID: id=20, offset=0, width=4  ->  imm = (width-1)<<11 | id
    int xcc = __builtin_amdgcn_s_getreg((3 << 11) | 20) & 7;

    for (int qi = 0; qi < 8; ++qi) {
        int s = (xcc + qi) & 7;
        const ushort* zs = z + (size_t)s * VN * 32 + l * 8;
        while (true) {
            if (tid == 0) sIdx = atomicAdd(qctr + s, 1);
            __syncthreads();
            int rb = sIdx;
            __syncthreads();
            if (rb >= TP_BX) break;
            int r = rb * 64 + rbase;
            if (r >= VN) continue;

            int e0 = row_ptr[r];
            int e1 = row_ptr[r + 1];
            float acc[8], acc2[8];
#pragma unroll
            for (int j = 0; j < 8; ++j) { acc[j] = 0.f; acc2[j] = 0.f; }

            int e = e0;
            for (; e + 3 < e1; e += 4) {
                unsigned long long d0 = epack[e];
                unsigned long long d1 = epack[e + 1];
                unsigned long long d2 = epack[e + 2];
                unsigned long long d3 = epack[e + 3];
                ushort8 z0 = *reinterpret_cast<const ushort8*>(zs + (size_t)(unsigned int)d0 * 32);
                ushort8 z1 = *reinterpret_cast<const ushort8*>(zs + (size_t)(unsigned int)d1 * 32);
                ushort8 z2 = *reinterpret_cast<const ushort8*>(zs + (size_t)(unsigned int)d2 * 32);
                ushort8 z3 = *reinterpret_cast<const ushort8*>(zs + (size_t)(unsigned int)d3 * 32);
                float w0 = __uint_as_float((unsigned int)(d0 >> 32));
                float w1 = __uint_as_float((unsigned int)(d1 >> 32));
                float w2 = __uint_as_float((unsigned int)(d2 >> 32));
                float w3 = __uint_as_float((unsigned int)(d3 >> 32));
#pragma unroll
                for (int j = 0; j < 8; ++j) acc[j] += w0 * bf2f(z0[j]);
#pragma unroll
                for (int j = 0; j < 8; ++j) acc2[j] += w1 * bf2f(z1[j]);
#pragma unroll
                for (int j = 0; j < 8; ++j) acc[j] += w2 * bf2f(z2[j]);
#pragma unroll
                for (int j = 0; j < 8; ++j) acc2[j] += w3 * bf2f(z3[j]);
            }
            for (; e < e1; ++e) {
                unsigned long long d = epack[e];
                ushort8 zz = *reinterpret_cast<const ushort8*>(zs + (size_t)(unsigned int)d * 32);
                float w = __uint_as_float((unsigned int)(d >> 32));
#pragma unroll
                for (int j = 0; j < 8; ++j) acc[j] += w * bf2f(zz[j]);
            }
#pragma unroll
            for (int j = 0; j < 8; ++j) acc[j] += acc2[j];

            size_t off = ((size_t)s * VN + r) * 32 + l * 8;
            ushort8 res;
            if (beta != 0.f) {
                ushort8 pv = *reinterpret_cast<const ushort8*>(prev + off);
#pragma unroll
                for (int j = 0; j < 8; ++j) res[j] = f2bf(alpha * acc[j] + beta * bf2f(pv[j]));
            } else {
#pragma unroll
                for (int j = 0; j < 8; ++j) res[j] = f2bf(alpha * acc[j]);
            }
            *reinterpret_cast<ushort8*>(out + off) = res;
        }
    }
}

// ---------------------------------------------------------------------------
// MFMA GEMM:  out[b,o,v] = sum_{kk=0..255} wT[o][kk] * xk(v, b-slice)[kk] + bias[o]
// xk in sliced layout [8 planes][VN][32]. LDS staging/swizzle and MFMA path
// unchanged (verified correct in round 1).
// ---------------------------------------------------------------------------
__global__ __launch_bounds__(256) void cheb_gemm_mfma(float* __restrict__ out,
                                                      const ushort* __restrict__ xbase,
                                                      const ushort* __restrict__ wT,
                                                      const float* __restrict__ bias) {
    __shared__ __align__(16) short lsA[128 * 64];
    __shared__ __align__(16) short lsB[128 * 64];

    int b = blockIdx.y;
    int v0 = blockIdx.x * 128;
    int tid = threadIdx.x;
    int lane = tid & 63;
    int w = tid >> 6;
    int mw = w & 1;
    int nw = w >> 1;
    int ln = lane & 15;
    int quad = lane >> 4;

    int srow = tid >> 1;
    int posBase = (tid & 1) * 4;

    floatx4 acc[4][4];
#pragma unroll
    for (int mi = 0; mi < 4; ++mi)
#pragma unroll
        for (int ni = 0; ni < 4; ++ni) acc[mi][ni] = (floatx4){0.f, 0.f, 0.f, 0.f};

    for (int kc = 0; kc < 4; ++kc) {
        __syncthreads();
        // stage A: wT rows (o)
#pragma unroll
        for (int j = 0; j < 4; ++j) {
            int pos = posBase + j;
            int g = pos ^ (srow & 7);
            uint4 val = *reinterpret_cast<const uint4*>(wT + (size_t)srow * 256 + kc * 64 + g * 8);
            *reinterpret_cast<uint4*>(&lsA[(srow * 8 + pos) * 8]) = val;
        }
        // stage B: xk bf16, sliced layout [plane][VN][32]
        {
            const ushort* xk = xbase + (size_t)kc * VN * FN;
            int v = v0 + srow;
            bool ok = (v < VN);
#pragma unroll
            for (int j = 0; j < 4; ++j) {
                int pos = posBase + j;
                int g = pos ^ (srow & 7);
                int p = b * 2 + (g >> 2);          // global feature plane
                const ushort* src = xk + ((size_t)p * VN + v) * 32 + (g & 3) * 8;
                uint4 val;
                if (ok) val = *reinterpret_cast<const uint4*>(src);
                else    val = make_uint4(0u, 0u, 0u, 0u);
                *reinterpret_cast<uint4*>(&lsB[(srow * 8 + pos) * 8]) = val;
            }
        }
        __syncthreads();

#pragma unroll
        for (int s = 0; s < 2; ++s) {
            short8 afr[4], bfr[4];
#pragma unroll
            for (int mi = 0; mi < 4; ++mi) {
                int r = mw * 64 + mi * 16 + ln;
                int pos = (s * 4 + quad) ^ (r & 7);
                afr[mi] = *reinterpret_cast<const short8*>(&lsA[(r * 8 + pos) * 8]);
            }
#pragma unroll
            for (int ni = 0; ni < 4; ++ni) {
                int r = nw * 64 + ni * 16 + ln;
                int pos = (s * 4 + quad) ^ (r & 7);
                bfr[ni] = *reinterpret_cast<const short8*>(&lsB[(r * 8 + pos) * 8]);
            }
#pragma unroll
            for (int mi = 0; mi < 4; ++mi)
#pragma unroll
                for (int ni = 0; ni < 4; ++ni)
                    acc[mi][ni] = __builtin_amdgcn_mfma_f32_16x16x32_bf16(
                        afr[mi], bfr[ni], acc[mi][ni], 0, 0, 0);
        }
    }

#pragma unroll
    for (int mi = 0; mi < 4; ++mi) {
#pragma unroll
        for (int r = 0; r < 4; ++r) {
            int o = mw * 64 + mi * 16 + quad * 4 + r;
            float bv = bias[o];
            size_t obase = (size_t)(b * COUTN + o) * VN;
#pragma unroll
            for (int ni = 0; ni < 4; ++ni) {
                int v = v0 + nw * 64 + ni * 16 + ln;
                if (v < VN) out[obase + v] = acc[mi][ni][r] + bv;
            }
        }
    }
}

// ---------------------------------------------------------------------------
extern "C" void kernel_launch(void* const* d_in, const int* in_sizes, int n_in,
                              void* d_out, int out_size, void* d_ws, size_t ws_size,
                              hipStream_t stream) {
    const float* x        = (const float*)d_in[0];
    const int*   lap_rows = (const int*)d_in[1];
    const int*   lap_cols = (const int*)d_in[2];
    const float* lap_vals = (const float*)d_in[3];
    const float* weight   = (const float*)d_in[4];
    const float* bias     = (const float*)d_in[5];
    float* out = (float*)d_out;

    char* ws = (char*)d_ws;
    ushort* x0 = (ushort*)ws;                        // 4 x [8][V][32] bf16, contiguous
    ushort* x1 = x0 + (size_t)VN * FN;
    ushort* x2 = x1 + (size_t)VN * FN;
    ushort* x3 = x2 + (size_t)VN * FN;
    size_t xbytes = (size_t)4 * VN * FN * sizeof(ushort);
    int* row_ptr = (int*)(ws + xbytes);              // V+1 ints
    size_t rp_end = xbytes + (size_t)(VN + 1) * sizeof(int);
    rp_end = (rp_end + 15) & ~(size_t)15;            // 16B align
    ushort* wT = (ushort*)(ws + rp_end);             // (128,256) bf16 = 64KB
    size_t wt_end = rp_end + (size_t)COUTN * FN * sizeof(ushort);
    unsigned long long* epack = (unsigned long long*)(ws + wt_end);  // 6.4MB
    int* qctr = (int*)(ws + wt_end + (size_t)EN * sizeof(unsigned long long));  // 24 ints

    setup_fused<<<RP_BLOCKS + WT_BLOCKS + EP_BLOCKS + TP_BLOCKS, 256, 0, stream>>>(
        lap_rows, row_ptr, weight, wT, x, x0, lap_cols, lap_vals, epack, qctr);
    // x1 = L x0
    spmm_sliced<<<SPMM_GRID, 256, 0, stream>>>(x1, x0, x0, row_ptr, epack, qctr + 0, 1.f, 0.f);
    // x2 = 2 L x1 - x0
    spmm_sliced<<<SPMM_GRID, 256, 0, stream>>>(x2, x1, x0, row_ptr, epack, qctr + 8, 2.f, -1.f);
    // x3 = 2 L x2 - x1
    spmm_sliced<<<SPMM_GRID, 256, 0, stream>>>(x3, x2, x1, row_ptr, epack, qctr + 16, 2.f, -1.f);
    // out = sum_k xk @ Wk + bias  (MFMA)
    cheb_gemm_mfma<<<dim3((VN + 127) / 128, BN), 256, 0, stream>>>(out, x0, wT, bias);
}

// Round 4
// 374.777 us; speedup vs baseline: 2.4913x; 2.4913x over previous
//
#include <hip/hip_runtime.h>
#include <hip/hip_bf16.h>

#define VN 50000
#define EN 800000
#define BN 4
#define CINN 64
#define COUTN 128
#define KN 4
#define FN 256  // BN * CINN

typedef __attribute__((ext_vector_type(8))) short short8;
typedef __attribute__((ext_vector_type(8))) unsigned short ushort8;
typedef __attribute__((ext_vector_type(4))) float floatx4;

__device__ __forceinline__ float bf2f(unsigned short u) {
    union { unsigned int i; float f; } c;
    c.i = ((unsigned int)u) << 16;
    return c.f;
}
__device__ __forceinline__ unsigned short f2bf(float f) {
    __hip_bfloat16 h = __float2bfloat16(f);
    return *reinterpret_cast<unsigned short*>(&h);
}

#define RP_BLOCKS 196    // (VN+1+255)/256
#define WT_BLOCKS 128    // 128*256/256
#define EP_BLOCKS 3125   // EN/256
#define TP_BX 782        // (VN+63)/64
#define TP_BLOCKS (TP_BX * 4)

// ---------------------------------------------------------------------------
// Fused setup: [0,RP) row_ptr lower_bound; [RP,RP+WT) wT transpose+bf16;
// [..,+EP) packed (col,val) 8B edge records; rest: 64x64 x-transpose
// fp32->bf16 into interleaved layout x0[v][256] (round-0 layout, known-good).
// ---------------------------------------------------------------------------
__global__ __launch_bounds__(256) void setup_fused(const int* __restrict__ rows,
                                                   int* __restrict__ row_ptr,
                                                   const float* __restrict__ w,
                                                   ushort* __restrict__ wT,
                                                   const float* __restrict__ x,
                                                   ushort* __restrict__ x0,
                                                   const int* __restrict__ cols,
                                                   const float* __restrict__ vals,
                                                   unsigned long long* __restrict__ epack) {
    __shared__ float tile[64][65];
    int blk = blockIdx.x;
    int tid = threadIdx.x;
    if (blk < RP_BLOCKS) {
        int v = blk * 256 + tid;
        if (v > VN) return;
        int lo = 0, hi = EN;
        while (lo < hi) {
            int mid = (lo + hi) >> 1;
            if (rows[mid] < v) lo = mid + 1; else hi = mid;
        }
        row_ptr[v] = lo;
        return;
    }
    if (blk < RP_BLOCKS + WT_BLOCKS) {
        int idx = (blk - RP_BLOCKS) * 256 + tid;  // 32768 total
        int o = idx >> 8;
        int kk = idx & 255;
        wT[idx] = f2bf(w[(size_t)kk * COUTN + o]);
        return;
    }
    if (blk < RP_BLOCKS + WT_BLOCKS + EP_BLOCKS) {
        int idx = (blk - RP_BLOCKS - WT_BLOCKS) * 256 + tid;  // 800000 total
        unsigned int c = (unsigned int)cols[idx];
        unsigned int wv = __float_as_uint(vals[idx]);
        epack[idx] = ((unsigned long long)wv << 32) | (unsigned long long)c;
        return;
    }
    int t = blk - RP_BLOCKS - WT_BLOCKS - EP_BLOCKS;
    int v0 = (t % TP_BX) * 64;
    int f0 = (t / TP_BX) * 64;
    int tx = tid & 63;
    int ty = tid >> 6;
#pragma unroll
    for (int r = 0; r < 16; ++r) {
        int f = f0 + ty + r * 4;
        int v = v0 + tx;
        if (v < VN) tile[ty + r * 4][tx] = x[(size_t)f * VN + v];
    }
    __syncthreads();
#pragma unroll
    for (int r = 0; r < 16; ++r) {
        int v = v0 + ty + r * 4;
        int f = f0 + tx;
        if (v < VN) x0[(size_t)v * FN + f] = f2bf(tile[tx][ty + r * 4]);
    }
}

// ---------------------------------------------------------------------------
// bf16 SpMM (round-0 structure, known-good): out[v,:] = alpha * sum_e
// vals[e]*z[cols[e],:] + beta * prev[v,:].  One wave per vertex; lanes 0-31
// even edges, 32-63 odd. Each lane owns 8 bf16 features (16B gather).
// 4-deep gather pipeline per half -> 4 gathers in flight per wave. fp32
// accum, butterfly merge, bf16 store.
// Deltas vs round 0: (1) single 8B epack load per edge instead of separate
// cols[]+vals[] loads; (2) beta==0 pass skips the dead prev read.
// ---------------------------------------------------------------------------
__global__ __launch_bounds__(256) void spmm_cheb_bf16(ushort* __restrict__ out,
                                                      const ushort* __restrict__ z,
                                                      const ushort* __restrict__ prev,
                                                      const int* __restrict__ row_ptr,
                                                      const unsigned long long* __restrict__ epack,
                                                      float alpha, float beta) {
    int row = (int)((blockIdx.x * blockDim.x + threadIdx.x) >> 6);
    int lane = threadIdx.x & 63;
    if (row >= VN) return;
    int e0 = row_ptr[row];
    int e1 = row_ptr[row + 1];
    int half = lane >> 5;        // 0: even edges, 1: odd edges
    int fl = (lane & 31) * 8;    // 8 features per lane

    float acc0[8], acc1[8];
#pragma unroll
    for (int j = 0; j < 8; ++j) { acc0[j] = 0.f; acc1[j] = 0.f; }

    int e = e0 + half;
    // 4-deep main loop: 4 gathers in flight per half
    for (; e + 6 < e1; e += 8) {
        unsigned long long d0 = epack[e];
        unsigned long long d1 = epack[e + 2];
        unsigned long long d2 = epack[e + 4];
        unsigned long long d3 = epack[e + 6];
        ushort8 z0 = *reinterpret_cast<const ushort8*>(z + (size_t)(unsigned int)d0 * FN + fl);
        ushort8 z1 = *reinterpret_cast<const ushort8*>(z + (size_t)(unsigned int)d1 * FN + fl);
        ushort8 z2 = *reinterpret_cast<const ushort8*>(z + (size_t)(unsigned int)d2 * FN + fl);
        ushort8 z3 = *reinterpret_cast<const ushort8*>(z + (size_t)(unsigned int)d3 * FN + fl);
        float w0 = __uint_as_float((unsigned int)(d0 >> 32));
        float w1 = __uint_as_float((unsigned int)(d1 >> 32));
        float w2 = __uint_as_float((unsigned int)(d2 >> 32));
        float w3 = __uint_as_float((unsigned int)(d3 >> 32));
#pragma unroll
        for (int j = 0; j < 8; ++j) acc0[j] += w0 * bf2f(z0[j]);
#pragma unroll
        for (int j = 0; j < 8; ++j) acc1[j] += w1 * bf2f(z1[j]);
#pragma unroll
        for (int j = 0; j < 8; ++j) acc0[j] += w2 * bf2f(z2[j]);
#pragma unroll
        for (int j = 0; j < 8; ++j) acc1[j] += w3 * bf2f(z3[j]);
    }
    // 2-deep remainder
    for (; e + 2 < e1; e += 4) {
        unsigned long long d0 = epack[e];
        unsigned long long d1 = epack[e + 2];
        ushort8 z0 = *reinterpret_cast<const ushort8*>(z + (size_t)(unsigned int)d0 * FN + fl);
        ushort8 z1 = *reinterpret_cast<const ushort8*>(z + (size_t)(unsigned int)d1 * FN + fl);
        float w0 = __uint_as_float((unsigned int)(d0 >> 32));
        float w1 = __uint_as_float((unsigned int)(d1 >> 32));
#pragma unroll
        for (int j = 0; j < 8; ++j) acc0[j] += w0 * bf2f(z0[j]);
#pragma unroll
        for (int j = 0; j < 8; ++j) acc1[j] += w1 * bf2f(z1[j]);
    }
    for (; e < e1; e += 2) {
        unsigned long long d0 = epack[e];
        ushort8 z0 = *reinterpret_cast<const ushort8*>(z + (size_t)(unsigned int)d0 * FN + fl);
        float w0 = __uint_as_float((unsigned int)(d0 >> 32));
#pragma unroll
        for (int j = 0; j < 8; ++j) acc0[j] += w0 * bf2f(z0[j]);
    }
#pragma unroll
    for (int j = 0; j < 8; ++j) acc0[j] += acc1[j];
    // butterfly: merge even/odd halves
#pragma unroll
    for (int j = 0; j < 8; ++j) acc0[j] += __shfl(acc0[j], lane ^ 32);

    if (half == 0) {
        ushort8 res;
        if (beta != 0.f) {
            ushort8 pv = *reinterpret_cast<const ushort8*>(prev + (size_t)row * FN + fl);
#pragma unroll
            for (int j = 0; j < 8; ++j)
                res[j] = f2bf(alpha * acc0[j] + beta * bf2f(pv[j]));
        } else {
#pragma unroll
            for (int j = 0; j < 8; ++j)
                res[j] = f2bf(alpha * acc0[j]);
        }
        *reinterpret_cast<ushort8*>(out + (size_t)row * FN + fl) = res;
    }
}

// ---------------------------------------------------------------------------
// MFMA GEMM (round-0, known-good):
// out[b,o,v] = sum_{kk=0..255} wT[o][kk] * xk(v, b-slice)[kk] + bias[o]
// A = wT (M=o=128), B = x rows (N=v, 128/block), bf16. K chunk = 64 (one
// Chebyshev term). LDS [row][64 bf16], 16B-granule XOR swizzle.
// D: col(lane&15)=v -> coalesced stores.
// ---------------------------------------------------------------------------
__global__ __launch_bounds__(256) void cheb_gemm_mfma(float* __restrict__ out,
                                                      const ushort* __restrict__ xbase,
                                                      const ushort* __restrict__ wT,
                                                      const float* __restrict__ bias) {
    __shared__ __align__(16) short lsA[128 * 64];
    __shared__ __align__(16) short lsB[128 * 64];

    int b = blockIdx.y;
    int v0 = blockIdx.x * 128;
    int tid = threadIdx.x;
    int lane = tid & 63;
    int w = tid >> 6;
    int mw = w & 1;
    int nw = w >> 1;
    int ln = lane & 15;
    int quad = lane >> 4;

    int srow = tid >> 1;
    int posBase = (tid & 1) * 4;

    floatx4 acc[4][4];
#pragma unroll
    for (int mi = 0; mi < 4; ++mi)
#pragma unroll
        for (int ni = 0; ni < 4; ++ni) acc[mi][ni] = (floatx4){0.f, 0.f, 0.f, 0.f};

    for (int kc = 0; kc < 4; ++kc) {
        __syncthreads();
        // stage A: wT rows (o)
#pragma unroll
        for (int j = 0; j < 4; ++j) {
            int pos = posBase + j;
            int g = pos ^ (srow & 7);
            uint4 val = *reinterpret_cast<const uint4*>(wT + (size_t)srow * 256 + kc * 64 + g * 8);
            *reinterpret_cast<uint4*>(&lsA[(srow * 8 + pos) * 8]) = val;
        }
        // stage B: xk bf16 direct copy
        {
            const ushort* xk = xbase + (size_t)kc * VN * FN;
            int v = v0 + srow;
            bool ok = (v < VN);
            const ushort* src = xk + (size_t)v * FN + b * CINN;
#pragma unroll
            for (int j = 0; j < 4; ++j) {
                int pos = posBase + j;
                int g = pos ^ (srow & 7);
                uint4 val;
                if (ok) val = *reinterpret_cast<const uint4*>(src + g * 8);
                else    val = make_uint4(0u, 0u, 0u, 0u);
                *reinterpret_cast<uint4*>(&lsB[(srow * 8 + pos) * 8]) = val;
            }
        }
        __syncthreads();

#pragma unroll
        for (int s = 0; s < 2; ++s) {
            short8 afr[4], bfr[4];
#pragma unroll
            for (int mi = 0; mi < 4; ++mi) {
                int r = mw * 64 + mi * 16 + ln;
                int pos = (s * 4 + quad) ^ (r & 7);
                afr[mi] = *reinterpret_cast<const short8*>(&lsA[(r * 8 + pos) * 8]);
            }
#pragma unroll
            for (int ni = 0; ni < 4; ++ni) {
                int r = nw * 64 + ni * 16 + ln;
                int pos = (s * 4 + quad) ^ (r & 7);
                bfr[ni] = *reinterpret_cast<const short8*>(&lsB[(r * 8 + pos) * 8]);
            }
#pragma unroll
            for (int mi = 0; mi < 4; ++mi)
#pragma unroll
                for (int ni = 0; ni < 4; ++ni)
                    acc[mi][ni] = __builtin_amdgcn_mfma_f32_16x16x32_bf16(
                        afr[mi], bfr[ni], acc[mi][ni], 0, 0, 0);
        }
    }

#pragma unroll
    for (int mi = 0; mi < 4; ++mi) {
#pragma unroll
        for (int r = 0; r < 4; ++r) {
            int o = mw * 64 + mi * 16 + quad * 4 + r;
            float bv = bias[o];
            size_t obase = (size_t)(b * COUTN + o) * VN;
#pragma unroll
            for (int ni = 0; ni < 4; ++ni) {
                int v = v0 + nw * 64 + ni * 16 + ln;
                if (v < VN) out[obase + v] = acc[mi][ni][r] + bv;
            }
        }
    }
}

// ---------------------------------------------------------------------------
extern "C" void kernel_launch(void* const* d_in, const int* in_sizes, int n_in,
                              void* d_out, int out_size, void* d_ws, size_t ws_size,
                              hipStream_t stream) {
    const float* x        = (const float*)d_in[0];
    const int*   lap_rows = (const int*)d_in[1];
    const int*   lap_cols = (const int*)d_in[2];
    const float* lap_vals = (const float*)d_in[3];
    const float* weight   = (const float*)d_in[4];
    const float* bias     = (const float*)d_in[5];
    float* out = (float*)d_out;

    char* ws = (char*)d_ws;
    ushort* x0 = (ushort*)ws;                        // 4 x (V,256) bf16, contiguous
    ushort* x1 = x0 + (size_t)VN * FN;
    ushort* x2 = x1 + (size_t)VN * FN;
    ushort* x3 = x2 + (size_t)VN * FN;
    size_t xbytes = (size_t)4 * VN * FN * sizeof(ushort);
    int* row_ptr = (int*)(ws + xbytes);              // V+1 ints
    size_t rp_end = xbytes + (size_t)(VN + 1) * sizeof(int);
    rp_end = (rp_end + 15) & ~(size_t)15;            // 16B align
    ushort* wT = (ushort*)(ws + rp_end);             // (128,256) bf16 = 64KB
    size_t wt_end = rp_end + (size_t)COUTN * FN * sizeof(ushort);
    unsigned long long* epack = (unsigned long long*)(ws + wt_end);  // 6.4MB

    setup_fused<<<RP_BLOCKS + WT_BLOCKS + EP_BLOCKS + TP_BLOCKS, 256, 0, stream>>>(
        lap_rows, row_ptr, weight, wT, x, x0, lap_cols, lap_vals, epack);
    // x1 = L x0
    spmm_cheb_bf16<<<(VN + 3) / 4, 256, 0, stream>>>(x1, x0, x0, row_ptr, epack, 1.f, 0.f);
    // x2 = 2 L x1 - x0
    spmm_cheb_bf16<<<(VN + 3) / 4, 256, 0, stream>>>(x2, x1, x0, row_ptr, epack, 2.f, -1.f);
    // x3 = 2 L x2 - x1
    spmm_cheb_bf16<<<(VN + 3) / 4, 256, 0, stream>>>(x3, x2, x1, row_ptr, epack, 2.f, -1.f);
    // out = sum_k xk @ Wk + bias  (MFMA)
    cheb_gemm_mfma<<<dim3((VN + 127) / 128, BN), 256, 0, stream>>>(out, x0, wT, bias);
}